// Round 13
// baseline (412.438 us; speedup 1.0000x reference)
//
#include <hip/hip_runtime.h>
#include <hip/hip_bf16.h>
#include <stdint.h>

// MLA forward, bf16 MFMA pipeline. Prefill-optimal DECOMPRESSED attention:
// K_h = [kvn @ wkvb_nope^T | rope(k_pe)] (192-dim), V2T_h = wkvb_v @ kvn^T.
// Softmax fused into the GEMMs: QK epilogue writes P_unnorm = exp(s*scale)
// (masked) + atomicAdd row sums; PV epilogue normalizes by 1/rowsum.
// BM=64 GEMMs use a 3-deep LDS pipeline with counted vmcnt (T4).
// Shapes: B=1 S=2048 HID=2048 H=16 QLR=1536 KVLR=512 NOPE=128 ROPE=64 VD=128 QKD=192.

using bf16 = __hip_bfloat16;
typedef __bf16 bf16x8 __attribute__((ext_vector_type(8)));
typedef __bf16 bf16x4 __attribute__((ext_vector_type(4)));
typedef float f32x4 __attribute__((ext_vector_type(4)));

#define S_LEN 2048
#define NHEAD 16

static __device__ __forceinline__ void gload16(const void* g, void* l) {
  __builtin_amdgcn_global_load_lds(
      (const __attribute__((address_space(1))) unsigned int*)g,
      (__attribute__((address_space(3))) unsigned int*)l, 16, 0, 0);
}

// ------ fused fp32 -> bf16 converts (6 tensors) + rowsum zeroing, 1 launch --
__global__ void cvt_all(const float* __restrict__ x, const float* __restrict__ wqa_s,
                        const float* __restrict__ wqb_s, const float* __restrict__ wkva_s,
                        const float* __restrict__ wkvb_s, const float* __restrict__ wo_s,
                        bf16* __restrict__ xb, bf16* __restrict__ wqa,
                        bf16* __restrict__ wqb, bf16* __restrict__ wkva,
                        bf16* __restrict__ wkvb, bf16* __restrict__ wob,
                        float* __restrict__ rowsum) {
  // segment sizes in float4 units
  const size_t n0 = 1048576;           // x     2048x2048
  const size_t n1 = n0 + 786432;       // wq_a  1536x2048
  const size_t n2 = n1 + 1179648;      // wq_b  3072x1536
  const size_t n3 = n2 + 327680;       // wkv_a 576x2048 padded to 640 rows
  const size_t n4 = n3 + 524288;       // wkv_b 4096x512
  const size_t n5 = n4 + 1048576;      // wo    2048x2048
  const size_t n6 = n5 + 8192;         // rowsum 16x2048 f32 -> zero
  auto cvt4 = [](const float4 v, bf16* d) {
    bf16x4 o;
    o[0] = (__bf16)__float2bfloat16(v.x);
    o[1] = (__bf16)__float2bfloat16(v.y);
    o[2] = (__bf16)__float2bfloat16(v.z);
    o[3] = (__bf16)__float2bfloat16(v.w);
    *(bf16x4*)d = o;
  };
  for (size_t i = (size_t)blockIdx.x * blockDim.x + threadIdx.x; i < n6;
       i += (size_t)gridDim.x * blockDim.x) {
    if (i < n0) {
      cvt4(*(const float4*)(x + i * 4), xb + i * 4);
    } else if (i < n1) {
      size_t j = i - n0;
      cvt4(*(const float4*)(wqa_s + j * 4), wqa + j * 4);
    } else if (i < n2) {
      size_t j = i - n1;
      cvt4(*(const float4*)(wqb_s + j * 4), wqb + j * 4);
    } else if (i < n3) {
      size_t j = i - n2;
      size_t e = j * 4;
      int r = (int)(e / 2048), c = (int)(e % 2048);
      float4 v = (r < 576) ? *(const float4*)(wkva_s + (size_t)r * 2048 + c)
                           : make_float4(0.f, 0.f, 0.f, 0.f);
      cvt4(v, wkva + e);
    } else if (i < n4) {
      size_t j = i - n3;
      cvt4(*(const float4*)(wkvb_s + j * 4), wkvb + j * 4);
    } else if (i < n5) {
      size_t j = i - n4;
      cvt4(*(const float4*)(wo_s + j * 4), wob + j * 4);
    } else {
      size_t j = i - n5;
      *(float4*)(rowsum + j * 4) = make_float4(0.f, 0.f, 0.f, 0.f);
    }
  }
}

// ---------------- row RMSNorm (bf16 in -> bf16 out) -------------------------
__global__ void rmsnorm_bf16(const bf16* __restrict__ in, const float* __restrict__ w,
                             bf16* __restrict__ out, int cols) {
  const int r = blockIdx.x, tid = threadIdx.x;
  const bf16* row = in + (size_t)r * cols;
  float ss = 0.f;
  for (int c = tid; c < cols; c += 256) {
    float v = __bfloat162float(row[c]);
    ss += v * v;
  }
  for (int m = 32; m >= 1; m >>= 1) ss += __shfl_xor(ss, m, 64);
  __shared__ float red[4];
  if ((tid & 63) == 0) red[tid >> 6] = ss;
  __syncthreads();
  ss = red[0] + red[1] + red[2] + red[3];
  float inv = rsqrtf(ss / (float)cols + 1e-6f);
  for (int c = tid; c < cols; c += 256)
    out[(size_t)r * cols + c] = __float2bfloat16(__bfloat162float(row[c]) * inv * w[c]);
}

// ---- kv post: rmsnorm(kv) -> kvn[t][512]; rope(k_pe) -> Kh[h][t][128..192) --
__global__ void kv_post(const float* __restrict__ kvf, const float* __restrict__ kvw,
                        bf16* __restrict__ kvn, bf16* __restrict__ Kh) {
  const int t = blockIdx.x, tid = threadIdx.x;
  const float* row = kvf + (size_t)t * 640;
  float ss = 0.f;
  for (int c = tid; c < 512; c += 256) { float v = row[c]; ss += v * v; }
  for (int m = 32; m >= 1; m >>= 1) ss += __shfl_xor(ss, m, 64);
  __shared__ float red[4];
  if ((tid & 63) == 0) red[tid >> 6] = ss;
  __syncthreads();
  ss = red[0] + red[1] + red[2] + red[3];
  float inv = rsqrtf(ss * (1.0f / 512.0f) + 1e-6f);
  for (int c = tid; c < 512; c += 256)
    kvn[(size_t)t * 512 + c] = __float2bfloat16(row[c] * inv * kvw[c]);
  if (tid < 32) {
    const int j = tid;
    float freq = expf(-(float)j * (1.0f / 32.0f) * 9.210340371976184f); // ln(10000)
    float ang = (float)t * freq;
    float cs = cosf(ang), sn = sinf(ang);
    float x1 = row[512 + j];
    float x2 = row[512 + j + 32];
    bf16 o1 = __float2bfloat16(x1 * cs - x2 * sn);
    bf16 o2 = __float2bfloat16(x2 * cs + x1 * sn);
#pragma unroll
    for (int h = 0; h < 16; ++h) {
      bf16* kr = Kh + ((size_t)h * S_LEN + t) * 192 + 128;
      kr[j] = o1;
      kr[j + 32] = o2;
    }
  }
}

// ---------------- q rope, in-place on qv[s][h*192+128 .. +192) --------------
__global__ void q_rope(bf16* __restrict__ qv) {
  const int s = blockIdx.x, tid = threadIdx.x;
  for (int it = tid; it < 512; it += 256) {
    const int h = it >> 5, j = it & 31;
    float freq = expf(-(float)j * (1.0f / 32.0f) * 9.210340371976184f);
    float ang = (float)s * freq;
    float cs = cosf(ang), sn = sinf(ang);
    bf16* base = qv + (size_t)s * 3072 + h * 192 + 128;
    float x1 = __bfloat162float(base[j]);
    float x2 = __bfloat162float(base[j + 32]);
    base[j] = __float2bfloat16(x1 * cs - x2 * sn);
    base[j + 32] = __float2bfloat16(x2 * cs + x1 * sn);
  }
}

// ---------------- GEMM: C[m][n] = sum_k A[m][k]*B[n][k] (+bias[n]) ----------
// BM x 128 tile. BM=128: 4 waves, 2-buf + __syncthreads (2 blocks/CU).
//                BM=64:  2 waves, 3-buf + counted vmcnt(12) + raw s_barrier
//                        (72KB LDS, 2 blocks/CU, staging latency hidden 2 deep).
// T2 XOR-swizzled LDS (conflict-free b128 reads); XCD-aware bijective swizzle.
// mode 0: plain GEMM.
// mode 1 (QK): causal block-skip; epilogue writes exp(v*1/sqrt(192)) masked
//              (col<=row else 0) and atomicAdds row sums into rowsum[bz][row].
// mode 2 (PV): K clamped to m0+BM; bz-parity balanced pairing; epilogue
//              multiplies by 1/rowsum[bz][row].
template <bool BIAS, bool BF16OUT, int BM>
__global__ __launch_bounds__(BM == 64 ? 128 : 256)
void gemm_bt(const bf16* __restrict__ A, const bf16* __restrict__ B,
             const float* __restrict__ bias, void* __restrict__ Cv,
             int lda, int ldb, int ldc, int K, int Nreal,
             long long bA, long long bB, long long bC, int mode,
             float* __restrict__ rowsum) {
  // XCD swizzle: contiguous tile-chunk per XCD
  int bx, byi, bz;
  {
    const int gx = gridDim.x, gy = gridDim.y;
    const int nwg = gx * gy * (int)gridDim.z;
    const int lin = (int)blockIdx.x + gx * ((int)blockIdx.y + gy * (int)blockIdx.z);
    const int cpx = nwg >> 3;
    const int l2 = (lin & 7) * cpx + (lin >> 3);
    bx = l2 % gx;
    byi = (l2 / gx) % gy;
    bz = l2 / (gx * gy);
    if (mode == 1) byi = gy - 1 - byi;                      // heavy first
    if (mode == 2) byi = (bz & 1) ? byi : gy - 1 - byi;     // balanced pairs
  }
  const size_t m0 = (size_t)byi * BM, n0 = (size_t)bx * 128;
  if (mode == 1 && (int)n0 >= (int)m0 + BM) return;
  const int Keff = (mode == 2) ? ((K < (int)m0 + BM) ? K : (int)m0 + BM) : K;

  constexpr int NW = (BM == 64) ? 2 : 4;       // waves per block
  constexpr int ACH = BM / 8;                  // A 1KB chunks
  constexpr int PER = (ACH + 16) / NW;         // chunks per wave per stage
  constexpr int NBUF = (BM == 64) ? 3 : 2;
  static_assert(BM != 64 || PER == 12, "vmcnt literal assumes PER==12");
  __shared__ bf16 As[NBUF][BM * 64];
  __shared__ bf16 Bs[NBUF][8192];
  const int tid = threadIdx.x;
  const int wave = tid >> 6, lane = tid & 63;
  const int lo = lane & 15, hi = lane >> 4;
  const int wr = (BM == 64) ? 0 : (wave >> 1);
  const int wc = (BM == 64) ? wave : (wave & 1);
  A += (size_t)bz * (size_t)bA;
  B += (size_t)bz * (size_t)bB;
  const int srow = lane >> 3;                        // 0..7 (also row&7)
  const int scol = (((lane & 7) ^ srow) * 8);        // inverse-swizzled source col
  const int rsw = lo & 7;                            // read-side row&7

  auto stage = [&](int k0, int buf) {
#pragma unroll
    for (int i = 0; i < PER; ++i) {
      const int blk = wave * PER + i;
      if (blk < ACH) {
        const int row = blk * 8 + srow;
        gload16(A + (m0 + row) * (size_t)lda + k0 + scol, &As[buf][blk * 512]);
      } else {
        const int j = blk - ACH;
        const int row = j * 8 + srow;
        gload16(B + (n0 + row) * (size_t)ldb + k0 + scol, &Bs[buf][j * 512]);
      }
    }
  };

  f32x4 acc[4][4] = {};
  auto mma = [&](int cb) {
#pragma unroll
    for (int kk = 0; kk < 2; ++kk) {
      const int ch = (((kk << 2) + hi) ^ rsw) << 3;  // swizzled 16B chunk
      bf16x8 af[4], bfr[4];
#pragma unroll
      for (int m = 0; m < 4; ++m)
        af[m] = *(const bf16x8*)&As[cb][(wr * 64 + m * 16 + lo) * 64 + ch];
#pragma unroll
      for (int n = 0; n < 4; ++n)
        bfr[n] = *(const bf16x8*)&Bs[cb][(wc * 64 + n * 16 + lo) * 64 + ch];
#pragma unroll
      for (int m = 0; m < 4; ++m)
#pragma unroll
        for (int n = 0; n < 4; ++n)
          acc[m][n] = __builtin_amdgcn_mfma_f32_16x16x32_bf16(af[m], bfr[n], acc[m][n], 0, 0, 0);
    }
  };

  if constexpr (BM == 64) {
    // 3-deep: stage(t) waited via counted vmcnt (own 12 loads), stage(t+1)
    // stays in flight across the barrier; stage(t+2) issued after barrier.
    stage(0, 0);
    if (64 < Keff) stage(64, 1);
    int t = 0;
    for (int k0 = 0; k0 < Keff; k0 += 64, ++t) {
      if (k0 + 64 < Keff) asm volatile("s_waitcnt vmcnt(12)" ::: "memory");
      else                asm volatile("s_waitcnt vmcnt(0)" ::: "memory");
      __builtin_amdgcn_s_barrier();
      asm volatile("" ::: "memory");
      if (k0 + 128 < Keff) stage(k0 + 128, (t + 2) % 3);
      mma(t % 3);
    }
    // all waves finished their reads of the last buffer before epilogue
  } else {
    stage(0, 0);
    int cur = 0;
    for (int k0 = 0; k0 < Keff; k0 += 64) {
      __syncthreads();  // implicit vmcnt(0): buf[cur] ready; prev readers done
      if (k0 + 64 < Keff) stage(k0 + 64, cur ^ 1);
      mma(cur);
      cur ^= 1;
    }
  }

  float* Cf = (float*)Cv;
  bf16* Cb = (bf16*)Cv;
  const size_t cbase = (size_t)bz * (size_t)bC;
  const float* rs = (mode == 2) ? (rowsum + (size_t)bz * S_LEN) : nullptr;
  float ps[4][4] = {};  // mode 1 per-thread row partial sums (over this thread's cols)
#pragma unroll
  for (int m = 0; m < 4; ++m) {
    const size_t row = m0 + wr * 64 + m * 16 + hi * 4;
    float rin[4];
    if (mode == 2) {
#pragma unroll
      for (int j = 0; j < 4; ++j) rin[j] = 1.0f / rs[row + j];
    }
#pragma unroll
    for (int n = 0; n < 4; ++n) {
      const int col = (int)n0 + wc * 64 + n * 16 + lo;
      if (col < Nreal) {
        const float bv = BIAS ? bias[col] : 0.0f;
#pragma unroll
        for (int j = 0; j < 4; ++j) {
          float v = acc[m][n][j] + bv;
          if (mode == 1) {
            v = (col <= (int)(row + j)) ? __expf(v * 0.0721687836487032f) : 0.f;
            ps[m][j] += v;
          } else if (mode == 2) {
            v *= rin[j];
          }
          const size_t off = cbase + (row + j) * (size_t)ldc + col;
          if (BF16OUT) Cb[off] = __float2bfloat16(v);
          else         Cf[off] = v;
        }
      }
    }
  }
  if (mode == 1) {
    // reduce each row partial over the 16 'lo' lanes, one atomic per row slice
#pragma unroll
    for (int m = 0; m < 4; ++m)
#pragma unroll
      for (int j = 0; j < 4; ++j) {
        float s = ps[m][j];
        s += __shfl_xor(s, 1, 64);
        s += __shfl_xor(s, 2, 64);
        s += __shfl_xor(s, 4, 64);
        s += __shfl_xor(s, 8, 64);
        if (lo == 0)
          atomicAdd(rowsum + (size_t)bz * S_LEN + m0 + wr * 64 + m * 16 + hi * 4 + j, s);
      }
  }
}

// ---------------------------------------------------------------------------
extern "C" void kernel_launch(void* const* d_in, const int* in_sizes, int n_in,
                              void* d_out, int out_size, void* d_ws, size_t ws_size,
                              hipStream_t stream) {
  const float* x       = (const float*)d_in[0];
  const float* wq_a_w  = (const float*)d_in[1];
  const float* wq_a_b  = (const float*)d_in[2];
  const float* q_norm  = (const float*)d_in[3];
  const float* wq_b_w  = (const float*)d_in[4];
  const float* wq_b_b  = (const float*)d_in[5];
  const float* wkv_a_w = (const float*)d_in[6];
  const float* wkv_a_b = (const float*)d_in[7];
  const float* kv_norm = (const float*)d_in[8];
  const float* wkv_b_w = (const float*)d_in[9];
  const float* wo_w    = (const float*)d_in[10];
  const float* wo_bias = (const float*)d_in[11];
  float* out = (float*)d_out;

  char* base = (char*)d_ws;
  // Sbuf: 16 heads x 2048 x 2048 bf16 = 134,217,728 B at offset 0.
  // Transients (all dead before first QK write) alias INSIDE Sbuf:
  bf16*  Sbuf = (bf16*)(base);
  bf16*  xb   = (bf16*)(base + 0);          //  8,388,608
  bf16*  wqa  = (bf16*)(base + 8388608);    //  6,291,456
  bf16*  wqb  = (bf16*)(base + 14680064);   //  9,437,184
  bf16*  wkva = (bf16*)(base + 24117248);   //  2,621,440
  bf16*  wkvb = (bf16*)(base + 26738688);   //  4,194,304
  bf16*  qa   = (bf16*)(base + 30932992);   //  6,291,456
  bf16*  qn   = (bf16*)(base + 37224448);   //  6,291,456
  float* kvf  = (float*)(base + 43515904);  //  5,242,880
  bf16*  kvn  = (bf16*)(base + 48758784);   //  2,097,152  (end 50,855,936)
  // Persistent buffers after Sbuf:
  char* q = base + 134217728;
  bf16* qv     = (bf16*)(q);           q += 12582912;  // 2048x3072
  bf16* Kh     = (bf16*)(q);           q += 12582912;  // 16x2048x192
  bf16* V2T    = (bf16*)(q);           q += 8388608;   // 16x128x2048
  bf16* wob    = (bf16*)(q);           q += 8388608;   // 2048x2048
  bf16* oabs   = (bf16*)(q);           q += 8388608;   // 2048x2048
  float* rowsum = (float*)(q);         q += 131072;    // 16x2048 f32

  // all fp32->bf16 converts + rowsum zeroing in one launch
  cvt_all<<<dim3(2048), 256, 0, stream>>>(x, wq_a_w, wq_b_w, wkv_a_w, wkv_b_w, wo_w,
                                          xb, wqa, wqb, wkva, wkvb, wob, rowsum);

  // q_a = rmsnorm(x @ wq_a^T + b)
  gemm_bt<true, true, 64><<<dim3(12, 32, 1), 128, 0, stream>>>(
      xb, wqa, wq_a_b, qa, 2048, 2048, 1536, 2048, 1536, 0, 0, 0, 0, nullptr);
  rmsnorm_bf16<<<2048, 256, 0, stream>>>(qa, q_norm, qn, 1536);
  // q = qn @ wq_b^T + b -> qv [2048][3072] (16 heads x 192)
  gemm_bt<true, true, 128><<<dim3(24, 16, 1), 256, 0, stream>>>(
      qn, wqb, wq_b_b, qv, 1536, 1536, 3072, 1536, 3072, 0, 0, 0, 0, nullptr);
  q_rope<<<2048, 256, 0, stream>>>(qv);
  // kv_full = x @ wkv_a^T + b -> fp32 [2048][640] (576 valid)
  gemm_bt<true, false, 64><<<dim3(5, 32, 1), 128, 0, stream>>>(
      xb, wkva, wkv_a_b, kvf, 2048, 2048, 640, 2048, 576, 0, 0, 0, 0, nullptr);
  kv_post<<<2048, 256, 0, stream>>>(kvf, kv_norm, kvn, Kh);
  // K_h nope: Kh[h][t][0..128) = kvn[t] . wkvb[h*256+d][:]  (d<128)
  gemm_bt<false, true, 64><<<dim3(1, 32, 16), 128, 0, stream>>>(
      kvn, wkvb, nullptr, Kh, 512, 512, 192, 512, 128,
      0, 256ll * 512, 2048ll * 192, 0, nullptr);
  // V2T[h][d][t] = wkvb[h*256+128+d][:] . kvn[t][:]
  gemm_bt<false, true, 64><<<dim3(16, 2, 16), 128, 0, stream>>>(
      wkvb + 128ull * 512, kvn, nullptr, V2T, 512, 512, 2048, 512, 2048,
      256ll * 512, 0, 128ll * 2048, 0, nullptr);

  // ---- attention (decompressed, fused softmax), single pass, 16 heads ----
  // P_unnorm[h][q][t] = exp(q_h[q].K_h[t] * scale) masked; rowsum atomics
  gemm_bt<false, true, 128><<<dim3(16, 16, 16), 256, 0, stream>>>(
      qv, Kh, nullptr, Sbuf,
      3072, 192, 2048, 192, 2048,
      192ll, 2048ll * 192, 2048ll * 2048, 1, rowsum);
  // oabs[q][h*128+d] = (1/rowsum) * sum_t P_unnorm[h][q][t] * V2T[h][d][t]
  gemm_bt<false, true, 64><<<dim3(1, 32, 16), 128, 0, stream>>>(
      Sbuf, V2T, nullptr, oabs,
      2048, 2048, 2048, 2048, 128,
      2048ll * 2048, 128ll * 2048, 128ll, 2, rowsum);

  // final: out = oabs @ wo^T + b (fp32 out)
  gemm_bt<true, false, 64><<<dim3(16, 32, 1), 128, 0, stream>>>(
      oabs, wob, wo_bias, out, 2048, 2048, 2048, 2048, 2048, 0, 0, 0, 0, nullptr);
}

// Round 14
// 316.729 us; speedup vs baseline: 1.3022x; 1.3022x over previous
//
#include <hip/hip_runtime.h>
#include <hip/hip_bf16.h>
#include <stdint.h>

// MLA forward, bf16 MFMA pipeline. Prefill-optimal DECOMPRESSED attention:
// K_h = [kvn @ wkvb_nope^T | rope(k_pe)] (192-dim), V2T_h = wkvb_v @ kvn^T.
// S = q_h · K_h^T (causal GEMM) -> row softmax -> O = P · V2 straight into oabs.
// Single-pass 16-head attention; Sbuf (134MB) aliases prologue-dead buffers.
// GEMM LDS uses T2 XOR swizzle (conflict-free ds_read_b128). Modes 1/2 use
// bz-parity byi remap so each CU's co-resident block pair is heavy+light.
// Shapes: B=1 S=2048 HID=2048 H=16 QLR=1536 KVLR=512 NOPE=128 ROPE=64 VD=128 QKD=192.

using bf16 = __hip_bfloat16;
typedef __bf16 bf16x8 __attribute__((ext_vector_type(8)));
typedef __bf16 bf16x4 __attribute__((ext_vector_type(4)));
typedef float f32x4 __attribute__((ext_vector_type(4)));

#define S_LEN 2048
#define NHEAD 16

static __device__ __forceinline__ void gload16(const void* g, void* l) {
  __builtin_amdgcn_global_load_lds(
      (const __attribute__((address_space(1))) unsigned int*)g,
      (__attribute__((address_space(3))) unsigned int*)l, 16, 0, 0);
}

// ---------------- fused fp32 -> bf16 converts (all 6 tensors, 1 launch) -----
__global__ void cvt_all(const float* __restrict__ x, const float* __restrict__ wqa_s,
                        const float* __restrict__ wqb_s, const float* __restrict__ wkva_s,
                        const float* __restrict__ wkvb_s, const float* __restrict__ wo_s,
                        bf16* __restrict__ xb, bf16* __restrict__ wqa,
                        bf16* __restrict__ wqb, bf16* __restrict__ wkva,
                        bf16* __restrict__ wkvb, bf16* __restrict__ wob) {
  // segment sizes in float4 units
  const size_t n0 = 1048576;           // x     2048x2048
  const size_t n1 = n0 + 786432;       // wq_a  1536x2048
  const size_t n2 = n1 + 1179648;      // wq_b  3072x1536
  const size_t n3 = n2 + 327680;       // wkv_a 576x2048 padded to 640 rows
  const size_t n4 = n3 + 524288;       // wkv_b 4096x512
  const size_t n5 = n4 + 1048576;      // wo    2048x2048
  auto cvt4 = [](const float4 v, bf16* d) {
    bf16x4 o;
    o[0] = (__bf16)__float2bfloat16(v.x);
    o[1] = (__bf16)__float2bfloat16(v.y);
    o[2] = (__bf16)__float2bfloat16(v.z);
    o[3] = (__bf16)__float2bfloat16(v.w);
    *(bf16x4*)d = o;
  };
  for (size_t i = (size_t)blockIdx.x * blockDim.x + threadIdx.x; i < n5;
       i += (size_t)gridDim.x * blockDim.x) {
    if (i < n0) {
      cvt4(*(const float4*)(x + i * 4), xb + i * 4);
    } else if (i < n1) {
      size_t j = i - n0;
      cvt4(*(const float4*)(wqa_s + j * 4), wqa + j * 4);
    } else if (i < n2) {
      size_t j = i - n1;
      cvt4(*(const float4*)(wqb_s + j * 4), wqb + j * 4);
    } else if (i < n3) {
      size_t j = i - n2;
      size_t e = j * 4;
      int r = (int)(e / 2048), c = (int)(e % 2048);
      float4 v = (r < 576) ? *(const float4*)(wkva_s + (size_t)r * 2048 + c)
                           : make_float4(0.f, 0.f, 0.f, 0.f);
      cvt4(v, wkva + e);
    } else if (i < n4) {
      size_t j = i - n3;
      cvt4(*(const float4*)(wkvb_s + j * 4), wkvb + j * 4);
    } else {
      size_t j = i - n4;
      cvt4(*(const float4*)(wo_s + j * 4), wob + j * 4);
    }
  }
}

// ---------------- row RMSNorm (bf16 in -> bf16 out) -------------------------
__global__ void rmsnorm_bf16(const bf16* __restrict__ in, const float* __restrict__ w,
                             bf16* __restrict__ out, int cols) {
  const int r = blockIdx.x, tid = threadIdx.x;
  const bf16* row = in + (size_t)r * cols;
  float ss = 0.f;
  for (int c = tid; c < cols; c += 256) {
    float v = __bfloat162float(row[c]);
    ss += v * v;
  }
  for (int m = 32; m >= 1; m >>= 1) ss += __shfl_xor(ss, m, 64);
  __shared__ float red[4];
  if ((tid & 63) == 0) red[tid >> 6] = ss;
  __syncthreads();
  ss = red[0] + red[1] + red[2] + red[3];
  float inv = rsqrtf(ss / (float)cols + 1e-6f);
  for (int c = tid; c < cols; c += 256)
    out[(size_t)r * cols + c] = __float2bfloat16(__bfloat162float(row[c]) * inv * w[c]);
}

// ---- kv post: rmsnorm(kv) -> kvn[t][512]; rope(k_pe) -> Kh[h][t][128..192) --
__global__ void kv_post(const float* __restrict__ kvf, const float* __restrict__ kvw,
                        bf16* __restrict__ kvn, bf16* __restrict__ Kh) {
  const int t = blockIdx.x, tid = threadIdx.x;
  const float* row = kvf + (size_t)t * 640;
  float ss = 0.f;
  for (int c = tid; c < 512; c += 256) { float v = row[c]; ss += v * v; }
  for (int m = 32; m >= 1; m >>= 1) ss += __shfl_xor(ss, m, 64);
  __shared__ float red[4];
  if ((tid & 63) == 0) red[tid >> 6] = ss;
  __syncthreads();
  ss = red[0] + red[1] + red[2] + red[3];
  float inv = rsqrtf(ss * (1.0f / 512.0f) + 1e-6f);
  for (int c = tid; c < 512; c += 256)
    kvn[(size_t)t * 512 + c] = __float2bfloat16(row[c] * inv * kvw[c]);
  if (tid < 32) {
    const int j = tid;
    float freq = expf(-(float)j * (1.0f / 32.0f) * 9.210340371976184f); // ln(10000)
    float ang = (float)t * freq;
    float cs = cosf(ang), sn = sinf(ang);
    float x1 = row[512 + j];
    float x2 = row[512 + j + 32];
    bf16 o1 = __float2bfloat16(x1 * cs - x2 * sn);
    bf16 o2 = __float2bfloat16(x2 * cs + x1 * sn);
#pragma unroll
    for (int h = 0; h < 16; ++h) {
      bf16* kr = Kh + ((size_t)h * S_LEN + t) * 192 + 128;
      kr[j] = o1;
      kr[j + 32] = o2;
    }
  }
}

// ---------------- q rope, in-place on qv[s][h*192+128 .. +192) --------------
__global__ void q_rope(bf16* __restrict__ qv) {
  const int s = blockIdx.x, tid = threadIdx.x;
  for (int it = tid; it < 512; it += 256) {
    const int h = it >> 5, j = it & 31;
    float freq = expf(-(float)j * (1.0f / 32.0f) * 9.210340371976184f);
    float ang = (float)s * freq;
    float cs = cosf(ang), sn = sinf(ang);
    bf16* base = qv + (size_t)s * 3072 + h * 192 + 128;
    float x1 = __bfloat162float(base[j]);
    float x2 = __bfloat162float(base[j + 32]);
    base[j] = __float2bfloat16(x1 * cs - x2 * sn);
    base[j + 32] = __float2bfloat16(x2 * cs + x1 * sn);
  }
}

// ---------------- row softmax, causal, in-place on S[h][q][0..2048) ---------
// Reads/writes only t < padend = round_up(q+1, 128); zero-pads (q, padend).
__global__ void softmax_rows(bf16* __restrict__ S) {
  const int q = blockIdx.x, hh = blockIdx.y;
  bf16* row = S + ((size_t)hh * S_LEN + q) * S_LEN;
  const int tid = threadIdx.x, w = tid >> 6, lane = tid & 63;
  const int i0 = tid * 8;
  const int padend = ((q >> 7) + 1) << 7;
  __shared__ float red[4];
  bf16x8 in = {};
  if (i0 < padend) in = *(const bf16x8*)(row + i0);
  const float scale = 0.0721687836487032f;  // 1/sqrt(192)
  float v[8];
  float mx = -3e38f;
#pragma unroll
  for (int j = 0; j < 8; ++j) {
    v[j] = (i0 + j <= q) ? (float)in[j] * scale : -3e38f;
    mx = fmaxf(mx, v[j]);
  }
#pragma unroll
  for (int d = 1; d < 64; d <<= 1) mx = fmaxf(mx, __shfl_xor(mx, d, 64));
  if (lane == 0) red[w] = mx;
  __syncthreads();
  mx = fmaxf(fmaxf(red[0], red[1]), fmaxf(red[2], red[3]));
  __syncthreads();
  float p[8], sum = 0.f;
#pragma unroll
  for (int j = 0; j < 8; ++j) {
    p[j] = (i0 + j <= q) ? __expf(v[j] - mx) : 0.f;
    sum += p[j];
  }
#pragma unroll
  for (int d = 1; d < 64; d <<= 1) sum += __shfl_xor(sum, d, 64);
  if (lane == 0) red[w] = sum;
  __syncthreads();
  sum = red[0] + red[1] + red[2] + red[3];
  const float inv = 1.0f / sum;
  if (i0 < padend) {
    bf16x8 o8;
#pragma unroll
    for (int j = 0; j < 8; ++j) o8[j] = (__bf16)__float2bfloat16(p[j] * inv);
    *(bf16x8*)(row + i0) = o8;
  }
}

// ---------------- GEMM: C[m][n] = sum_k A[m][k]*B[n][k] (+bias[n]) ----------
// BM x 128 tile. BM=128: 4 waves, 64KB LDS, 2 blocks/CU.
//                BM=64:  2 waves, 48KB LDS, 3 blocks/CU.
// BK=64, mfma 16x16x32, double-buffered LDS, prefetch-before-compute, ONE
// barrier per k-step. T2 XOR-swizzle on the LDS tiles: linear LDS dest
// (global_load_lds requirement), inverse-swizzled GLOBAL source column
// ((lane&7)^(lane>>3)), swizzled ds_read chunk ((kk*4+hi)^(lo&7)) ->
// conflict-free b128 reads. XCD-aware bijective block swizzle.
// mode 0: plain. mode 1: causal skip (n0 >= m0+BM). mode 2: K clamped to
// m0+BM (PV over causal P). Modes 1/2 use bz-parity byi remap: the XCD
// swizzle pairs same-byi blocks (bz parity apart) on one CU; flipping the
// even-bz member to gy-1-byi makes every pair heavy+light (constant work).
template <bool BIAS, bool BF16OUT, int BM>
__global__ __launch_bounds__(BM == 64 ? 128 : 256)
void gemm_bt(const bf16* __restrict__ A, const bf16* __restrict__ B,
             const float* __restrict__ bias, void* __restrict__ Cv,
             int lda, int ldb, int ldc, int K, int Nreal,
             long long bA, long long bB, long long bC, int mode) {
  // XCD swizzle: contiguous tile-chunk per XCD
  int bx, byi, bz;
  {
    const int gx = gridDim.x, gy = gridDim.y;
    const int nwg = gx * gy * (int)gridDim.z;
    const int lin = (int)blockIdx.x + gx * ((int)blockIdx.y + gy * (int)blockIdx.z);
    const int cpx = nwg >> 3;
    const int l2 = (lin & 7) * cpx + (lin >> 3);
    bx = l2 % gx;
    byi = (l2 / gx) % gy;
    bz = l2 / (gx * gy);
    if (mode) byi = (bz & 1) ? byi : gy - 1 - byi;  // balanced heavy+light pairs
  }
  const size_t m0 = (size_t)byi * BM, n0 = (size_t)bx * 128;
  if (mode == 1 && (int)n0 >= (int)m0 + BM) return;
  const int Keff = (mode == 2) ? ((K < (int)m0 + BM) ? K : (int)m0 + BM) : K;

  constexpr int NW = (BM == 64) ? 2 : 4;       // waves per block
  constexpr int ACH = BM / 8;                  // A 1KB chunks
  constexpr int PER = (ACH + 16) / NW;         // chunks per wave
  __shared__ bf16 As[2][BM * 64];
  __shared__ bf16 Bs[2][8192];
  const int tid = threadIdx.x;
  const int wave = tid >> 6, lane = tid & 63;
  const int lo = lane & 15, hi = lane >> 4;
  const int wr = (BM == 64) ? 0 : (wave >> 1);
  const int wc = (BM == 64) ? wave : (wave & 1);
  A += (size_t)bz * (size_t)bA;
  B += (size_t)bz * (size_t)bB;
  const int srow = lane >> 3;                        // 0..7 (also row&7)
  const int scol = (((lane & 7) ^ srow) * 8);        // inverse-swizzled source col
  const int rsw = lo & 7;                            // read-side row&7

  auto stage = [&](int k0, int buf) {
#pragma unroll
    for (int i = 0; i < PER; ++i) {
      const int blk = wave * PER + i;
      if (blk < ACH) {
        const int row = blk * 8 + srow;
        gload16(A + (m0 + row) * (size_t)lda + k0 + scol, &As[buf][blk * 512]);
      } else {
        const int j = blk - ACH;
        const int row = j * 8 + srow;
        gload16(B + (n0 + row) * (size_t)ldb + k0 + scol, &Bs[buf][j * 512]);
      }
    }
  };

  f32x4 acc[4][4] = {};
  stage(0, 0);
  int cur = 0;
  for (int k0 = 0; k0 < Keff; k0 += 64) {
    __syncthreads();  // implicit vmcnt(0): buf[cur] ready; prev readers done
    if (k0 + 64 < Keff) stage(k0 + 64, cur ^ 1);
#pragma unroll
    for (int kk = 0; kk < 2; ++kk) {
      const int ch = (((kk << 2) + hi) ^ rsw) << 3;  // swizzled 16B chunk
      bf16x8 af[4], bfr[4];
#pragma unroll
      for (int m = 0; m < 4; ++m)
        af[m] = *(const bf16x8*)&As[cur][(wr * 64 + m * 16 + lo) * 64 + ch];
#pragma unroll
      for (int n = 0; n < 4; ++n)
        bfr[n] = *(const bf16x8*)&Bs[cur][(wc * 64 + n * 16 + lo) * 64 + ch];
#pragma unroll
      for (int m = 0; m < 4; ++m)
#pragma unroll
        for (int n = 0; n < 4; ++n)
          acc[m][n] = __builtin_amdgcn_mfma_f32_16x16x32_bf16(af[m], bfr[n], acc[m][n], 0, 0, 0);
    }
    cur ^= 1;
  }
  float* Cf = (float*)Cv;
  bf16* Cb = (bf16*)Cv;
  const size_t cbase = (size_t)bz * (size_t)bC;
#pragma unroll
  for (int m = 0; m < 4; ++m) {
    const size_t row = m0 + wr * 64 + m * 16 + hi * 4;
#pragma unroll
    for (int n = 0; n < 4; ++n) {
      const int col = (int)n0 + wc * 64 + n * 16 + lo;
      if (col < Nreal) {
        const float bv = BIAS ? bias[col] : 0.0f;
#pragma unroll
        for (int j = 0; j < 4; ++j) {
          const float v = acc[m][n][j] + bv;
          const size_t off = cbase + (row + j) * (size_t)ldc + col;
          if (BF16OUT) Cb[off] = __float2bfloat16(v);
          else         Cf[off] = v;
        }
      }
    }
  }
}

// ---------------------------------------------------------------------------
extern "C" void kernel_launch(void* const* d_in, const int* in_sizes, int n_in,
                              void* d_out, int out_size, void* d_ws, size_t ws_size,
                              hipStream_t stream) {
  const float* x       = (const float*)d_in[0];
  const float* wq_a_w  = (const float*)d_in[1];
  const float* wq_a_b  = (const float*)d_in[2];
  const float* q_norm  = (const float*)d_in[3];
  const float* wq_b_w  = (const float*)d_in[4];
  const float* wq_b_b  = (const float*)d_in[5];
  const float* wkv_a_w = (const float*)d_in[6];
  const float* wkv_a_b = (const float*)d_in[7];
  const float* kv_norm = (const float*)d_in[8];
  const float* wkv_b_w = (const float*)d_in[9];
  const float* wo_w    = (const float*)d_in[10];
  const float* wo_bias = (const float*)d_in[11];
  float* out = (float*)d_out;

  char* base = (char*)d_ws;
  // Sbuf: 16 heads x 2048 x 2048 bf16 = 134,217,728 B at offset 0.
  // Transients (all dead before first QK write) alias INSIDE Sbuf:
  bf16*  Sbuf = (bf16*)(base);
  bf16*  xb   = (bf16*)(base + 0);          //  8,388,608
  bf16*  wqa  = (bf16*)(base + 8388608);    //  6,291,456
  bf16*  wqb  = (bf16*)(base + 14680064);   //  9,437,184
  bf16*  wkva = (bf16*)(base + 24117248);   //  2,621,440
  bf16*  wkvb = (bf16*)(base + 26738688);   //  4,194,304
  bf16*  qa   = (bf16*)(base + 30932992);   //  6,291,456
  bf16*  qn   = (bf16*)(base + 37224448);   //  6,291,456
  float* kvf  = (float*)(base + 43515904);  //  5,242,880
  bf16*  kvn  = (bf16*)(base + 48758784);   //  2,097,152  (end 50,855,936)
  // Persistent buffers after Sbuf:
  char* q = base + 134217728;
  bf16* qv   = (bf16*)(q);             q += 12582912;  // 2048x3072
  bf16* Kh   = (bf16*)(q);             q += 12582912;  // 16x2048x192
  bf16* V2T  = (bf16*)(q);             q += 8388608;   // 16x128x2048
  bf16* wob  = (bf16*)(q);             q += 8388608;   // 2048x2048
  bf16* oabs = (bf16*)(q);             q += 8388608;   // 2048x2048

  // all fp32->bf16 converts in one launch
  cvt_all<<<dim3(2048), 256, 0, stream>>>(x, wq_a_w, wq_b_w, wkv_a_w, wkv_b_w, wo_w,
                                          xb, wqa, wqb, wkva, wkvb, wob);

  // q_a = rmsnorm(x @ wq_a^T + b)
  gemm_bt<true, true, 64><<<dim3(12, 32, 1), 128, 0, stream>>>(
      xb, wqa, wq_a_b, qa, 2048, 2048, 1536, 2048, 1536, 0, 0, 0, 0);
  rmsnorm_bf16<<<2048, 256, 0, stream>>>(qa, q_norm, qn, 1536);
  // q = qn @ wq_b^T + b -> qv [2048][3072] (16 heads x 192)
  gemm_bt<true, true, 128><<<dim3(24, 16, 1), 256, 0, stream>>>(
      qn, wqb, wq_b_b, qv, 1536, 1536, 3072, 1536, 3072, 0, 0, 0, 0);
  q_rope<<<2048, 256, 0, stream>>>(qv);
  // kv_full = x @ wkv_a^T + b -> fp32 [2048][640] (576 valid)
  gemm_bt<true, false, 64><<<dim3(5, 32, 1), 128, 0, stream>>>(
      xb, wkva, wkv_a_b, kvf, 2048, 2048, 640, 2048, 576, 0, 0, 0, 0);
  kv_post<<<2048, 256, 0, stream>>>(kvf, kv_norm, kvn, Kh);
  // K_h nope: Kh[h][t][0..128) = kvn[t] . wkvb[h*256+d][:]  (d<128)
  gemm_bt<false, true, 64><<<dim3(1, 32, 16), 128, 0, stream>>>(
      kvn, wkvb, nullptr, Kh, 512, 512, 192, 512, 128,
      0, 256ll * 512, 2048ll * 192, 0);
  // V2T[h][d][t] = wkvb[h*256+128+d][:] . kvn[t][:]
  gemm_bt<false, true, 64><<<dim3(16, 2, 16), 128, 0, stream>>>(
      wkvb + 128ull * 512, kvn, nullptr, V2T, 512, 512, 2048, 512, 2048,
      256ll * 512, 0, 128ll * 2048, 0);

  // ---- attention (decompressed, materialized S), single pass, 16 heads ----
  // S[h][q][t] = q_h[q] . K_h[t]  (K=192), causal block-skip
  gemm_bt<false, true, 128><<<dim3(16, 16, 16), 256, 0, stream>>>(
      qv, Kh, nullptr, Sbuf,
      3072, 192, 2048, 192, 2048,
      192ll, 2048ll * 192, 2048ll * 2048, 1);
  // in-place row softmax with causal mask + 128-tile zero-pad
  softmax_rows<<<dim3(2048, 16), 256, 0, stream>>>(Sbuf);
  // oabs[q][h*128+d] = sum_t P[h][q][t] * V2T[h][d][t], K clamped to m0+64
  gemm_bt<false, true, 64><<<dim3(1, 32, 16), 128, 0, stream>>>(
      Sbuf, V2T, nullptr, oabs,
      2048, 2048, 2048, 2048, 128,
      2048ll * 2048, 128ll * 2048, 128ll, 2);

  // final: out = oabs @ wo^T + b (fp32 out)
  gemm_bt<true, false, 64><<<dim3(16, 32, 1), 128, 0, stream>>>(
      oabs, wob, wo_bias, out, 2048, 2048, 2048, 2048, 2048, 0, 0, 0, 0);
}

// Round 15
// 252.351 us; speedup vs baseline: 1.6344x; 1.2551x over previous
//
#include <hip/hip_runtime.h>
#include <hip/hip_bf16.h>
#include <stdint.h>

// MLA forward, bf16 MFMA pipeline. Prefill-optimal DECOMPRESSED attention:
// K_h = [kvn @ wkvb_nope^T | rope(k_pe)] (192-dim), V2T_h = wkvb_v @ kvn^T.
// S = q_h · K_h^T (causal GEMM) -> row softmax -> O = P · V2 straight into oabs.
// Single-pass 16-head attention; Sbuf (134MB) aliases prologue-dead buffers.
// GEMM LDS uses T2 XOR swizzle (conflict-free ds_read_b128). BM=64 template
// now runs 4 waves (64x32 stripes) for 2x waves/CU latency hiding.
// Shapes: B=1 S=2048 HID=2048 H=16 QLR=1536 KVLR=512 NOPE=128 ROPE=64 VD=128 QKD=192.

using bf16 = __hip_bfloat16;
typedef __bf16 bf16x8 __attribute__((ext_vector_type(8)));
typedef __bf16 bf16x4 __attribute__((ext_vector_type(4)));
typedef float f32x4 __attribute__((ext_vector_type(4)));

#define S_LEN 2048
#define NHEAD 16

static __device__ __forceinline__ void gload16(const void* g, void* l) {
  __builtin_amdgcn_global_load_lds(
      (const __attribute__((address_space(1))) unsigned int*)g,
      (__attribute__((address_space(3))) unsigned int*)l, 16, 0, 0);
}

// ---------------- fused fp32 -> bf16 converts (all 6 tensors, 1 launch) -----
__global__ void cvt_all(const float* __restrict__ x, const float* __restrict__ wqa_s,
                        const float* __restrict__ wqb_s, const float* __restrict__ wkva_s,
                        const float* __restrict__ wkvb_s, const float* __restrict__ wo_s,
                        bf16* __restrict__ xb, bf16* __restrict__ wqa,
                        bf16* __restrict__ wqb, bf16* __restrict__ wkva,
                        bf16* __restrict__ wkvb, bf16* __restrict__ wob) {
  // segment sizes in float4 units
  const size_t n0 = 1048576;           // x     2048x2048
  const size_t n1 = n0 + 786432;       // wq_a  1536x2048
  const size_t n2 = n1 + 1179648;      // wq_b  3072x1536
  const size_t n3 = n2 + 327680;       // wkv_a 576x2048 padded to 640 rows
  const size_t n4 = n3 + 524288;       // wkv_b 4096x512
  const size_t n5 = n4 + 1048576;      // wo    2048x2048
  auto cvt4 = [](const float4 v, bf16* d) {
    bf16x4 o;
    o[0] = (__bf16)__float2bfloat16(v.x);
    o[1] = (__bf16)__float2bfloat16(v.y);
    o[2] = (__bf16)__float2bfloat16(v.z);
    o[3] = (__bf16)__float2bfloat16(v.w);
    *(bf16x4*)d = o;
  };
  for (size_t i = (size_t)blockIdx.x * blockDim.x + threadIdx.x; i < n5;
       i += (size_t)gridDim.x * blockDim.x) {
    if (i < n0) {
      cvt4(*(const float4*)(x + i * 4), xb + i * 4);
    } else if (i < n1) {
      size_t j = i - n0;
      cvt4(*(const float4*)(wqa_s + j * 4), wqa + j * 4);
    } else if (i < n2) {
      size_t j = i - n1;
      cvt4(*(const float4*)(wqb_s + j * 4), wqb + j * 4);
    } else if (i < n3) {
      size_t j = i - n2;
      size_t e = j * 4;
      int r = (int)(e / 2048), c = (int)(e % 2048);
      float4 v = (r < 576) ? *(const float4*)(wkva_s + (size_t)r * 2048 + c)
                           : make_float4(0.f, 0.f, 0.f, 0.f);
      cvt4(v, wkva + e);
    } else if (i < n4) {
      size_t j = i - n3;
      cvt4(*(const float4*)(wkvb_s + j * 4), wkvb + j * 4);
    } else {
      size_t j = i - n4;
      cvt4(*(const float4*)(wo_s + j * 4), wob + j * 4);
    }
  }
}

// ---------------- row RMSNorm (bf16 in -> bf16 out) -------------------------
__global__ void rmsnorm_bf16(const bf16* __restrict__ in, const float* __restrict__ w,
                             bf16* __restrict__ out, int cols) {
  const int r = blockIdx.x, tid = threadIdx.x;
  const bf16* row = in + (size_t)r * cols;
  float ss = 0.f;
  for (int c = tid; c < cols; c += 256) {
    float v = __bfloat162float(row[c]);
    ss += v * v;
  }
  for (int m = 32; m >= 1; m >>= 1) ss += __shfl_xor(ss, m, 64);
  __shared__ float red[4];
  if ((tid & 63) == 0) red[tid >> 6] = ss;
  __syncthreads();
  ss = red[0] + red[1] + red[2] + red[3];
  float inv = rsqrtf(ss / (float)cols + 1e-6f);
  for (int c = tid; c < cols; c += 256)
    out[(size_t)r * cols + c] = __float2bfloat16(__bfloat162float(row[c]) * inv * w[c]);
}

// ---- kv post: rmsnorm(kv) -> kvn[t][512]; rope(k_pe) -> Kh[h][t][128..192) --
__global__ void kv_post(const float* __restrict__ kvf, const float* __restrict__ kvw,
                        bf16* __restrict__ kvn, bf16* __restrict__ Kh) {
  const int t = blockIdx.x, tid = threadIdx.x;
  const float* row = kvf + (size_t)t * 640;
  float ss = 0.f;
  for (int c = tid; c < 512; c += 256) { float v = row[c]; ss += v * v; }
  for (int m = 32; m >= 1; m >>= 1) ss += __shfl_xor(ss, m, 64);
  __shared__ float red[4];
  if ((tid & 63) == 0) red[tid >> 6] = ss;
  __syncthreads();
  ss = red[0] + red[1] + red[2] + red[3];
  float inv = rsqrtf(ss * (1.0f / 512.0f) + 1e-6f);
  for (int c = tid; c < 512; c += 256)
    kvn[(size_t)t * 512 + c] = __float2bfloat16(row[c] * inv * kvw[c]);
  if (tid < 32) {
    const int j = tid;
    float freq = expf(-(float)j * (1.0f / 32.0f) * 9.210340371976184f); // ln(10000)
    float ang = (float)t * freq;
    float cs = cosf(ang), sn = sinf(ang);
    float x1 = row[512 + j];
    float x2 = row[512 + j + 32];
    bf16 o1 = __float2bfloat16(x1 * cs - x2 * sn);
    bf16 o2 = __float2bfloat16(x2 * cs + x1 * sn);
#pragma unroll
    for (int h = 0; h < 16; ++h) {
      bf16* kr = Kh + ((size_t)h * S_LEN + t) * 192 + 128;
      kr[j] = o1;
      kr[j + 32] = o2;
    }
  }
}

// ---------------- q rope, in-place on qv[s][h*192+128 .. +192) --------------
__global__ void q_rope(bf16* __restrict__ qv) {
  const int s = blockIdx.x, tid = threadIdx.x;
  for (int it = tid; it < 512; it += 256) {
    const int h = it >> 5, j = it & 31;
    float freq = expf(-(float)j * (1.0f / 32.0f) * 9.210340371976184f);
    float ang = (float)s * freq;
    float cs = cosf(ang), sn = sinf(ang);
    bf16* base = qv + (size_t)s * 3072 + h * 192 + 128;
    float x1 = __bfloat162float(base[j]);
    float x2 = __bfloat162float(base[j + 32]);
    base[j] = __float2bfloat16(x1 * cs - x2 * sn);
    base[j + 32] = __float2bfloat16(x2 * cs + x1 * sn);
  }
}

// ---------------- row softmax, causal, in-place on S[h][q][0..2048) ---------
// Reads/writes only t < padend = round_up(q+1, 128); zero-pads (q, padend).
__global__ void softmax_rows(bf16* __restrict__ S) {
  const int q = blockIdx.x, hh = blockIdx.y;
  bf16* row = S + ((size_t)hh * S_LEN + q) * S_LEN;
  const int tid = threadIdx.x, w = tid >> 6, lane = tid & 63;
  const int i0 = tid * 8;
  const int padend = ((q >> 7) + 1) << 7;
  __shared__ float red[4];
  bf16x8 in = {};
  if (i0 < padend) in = *(const bf16x8*)(row + i0);
  const float scale = 0.0721687836487032f;  // 1/sqrt(192)
  float v[8];
  float mx = -3e38f;
#pragma unroll
  for (int j = 0; j < 8; ++j) {
    v[j] = (i0 + j <= q) ? (float)in[j] * scale : -3e38f;
    mx = fmaxf(mx, v[j]);
  }
#pragma unroll
  for (int d = 1; d < 64; d <<= 1) mx = fmaxf(mx, __shfl_xor(mx, d, 64));
  if (lane == 0) red[w] = mx;
  __syncthreads();
  mx = fmaxf(fmaxf(red[0], red[1]), fmaxf(red[2], red[3]));
  __syncthreads();
  float p[8], sum = 0.f;
#pragma unroll
  for (int j = 0; j < 8; ++j) {
    p[j] = (i0 + j <= q) ? __expf(v[j] - mx) : 0.f;
    sum += p[j];
  }
#pragma unroll
  for (int d = 1; d < 64; d <<= 1) sum += __shfl_xor(sum, d, 64);
  if (lane == 0) red[w] = sum;
  __syncthreads();
  sum = red[0] + red[1] + red[2] + red[3];
  const float inv = 1.0f / sum;
  if (i0 < padend) {
    bf16x8 o8;
#pragma unroll
    for (int j = 0; j < 8; ++j) o8[j] = (__bf16)__float2bfloat16(p[j] * inv);
    *(bf16x8*)(row + i0) = o8;
  }
}

// ---------------- GEMM: C[m][n] = sum_k A[m][k]*B[n][k] (+bias[n]) ----------
// BM x 128 tile, 4 waves (256 thr) both variants.
//   BM=128: wave = 64x64 quadrant (acc[4][4]), 64KB LDS, 2 blocks/CU.
//   BM=64:  wave = 64x32 column stripe (acc[4][2]), 48KB LDS, 3 blocks/CU,
//           8-12 waves/CU for latency hiding.
// BK=64, mfma 16x16x32, double-buffered LDS, prefetch-before-compute, ONE
// barrier per k-step. T2 XOR-swizzle on LDS (linear dest for global_load_lds,
// inverse-swizzled global source col, swizzled ds_read chunk) -> conflict-free
// b128 reads. XCD-aware bijective block swizzle.
// mode 0: plain. mode 1: causal skip (n0 >= m0+BM). mode 2: K clamped to
// m0+BM. Modes 1/2: bz-parity byi remap (heavy+light pairing).
template <bool BIAS, bool BF16OUT, int BM>
__global__ __launch_bounds__(256)
void gemm_bt(const bf16* __restrict__ A, const bf16* __restrict__ B,
             const float* __restrict__ bias, void* __restrict__ Cv,
             int lda, int ldb, int ldc, int K, int Nreal,
             long long bA, long long bB, long long bC, int mode) {
  // XCD swizzle: contiguous tile-chunk per XCD
  int bx, byi, bz;
  {
    const int gx = gridDim.x, gy = gridDim.y;
    const int nwg = gx * gy * (int)gridDim.z;
    const int lin = (int)blockIdx.x + gx * ((int)blockIdx.y + gy * (int)blockIdx.z);
    const int cpx = nwg >> 3;
    const int l2 = (lin & 7) * cpx + (lin >> 3);
    bx = l2 % gx;
    byi = (l2 / gx) % gy;
    bz = l2 / (gx * gy);
    if (mode) byi = (bz & 1) ? byi : gy - 1 - byi;  // balanced heavy+light pairs
  }
  const size_t m0 = (size_t)byi * BM, n0 = (size_t)bx * 128;
  if (mode == 1 && (int)n0 >= (int)m0 + BM) return;
  const int Keff = (mode == 2) ? ((K < (int)m0 + BM) ? K : (int)m0 + BM) : K;

  constexpr int ACH = BM / 8;                  // A 1KB chunks
  constexpr int PER = (ACH + 16) / 4;          // chunks per wave (6 or 8)
  constexpr int NFR = (BM == 64) ? 2 : 4;      // n fragments per wave
  __shared__ bf16 As[2][BM * 64];
  __shared__ bf16 Bs[2][8192];
  const int tid = threadIdx.x;
  const int wave = tid >> 6, lane = tid & 63;
  const int lo = lane & 15, hi = lane >> 4;
  const int rowbase = (BM == 64) ? 0 : ((wave >> 1) * 64);
  const int colbase = (BM == 64) ? (wave * 32) : ((wave & 1) * 64);
  A += (size_t)bz * (size_t)bA;
  B += (size_t)bz * (size_t)bB;
  const int srow = lane >> 3;                        // 0..7 (also row&7)
  const int scol = (((lane & 7) ^ srow) * 8);        // inverse-swizzled source col
  const int rsw = lo & 7;                            // read-side row&7

  auto stage = [&](int k0, int buf) {
#pragma unroll
    for (int i = 0; i < PER; ++i) {
      const int blk = wave * PER + i;
      if (blk < ACH) {
        const int row = blk * 8 + srow;
        gload16(A + (m0 + row) * (size_t)lda + k0 + scol, &As[buf][blk * 512]);
      } else {
        const int j = blk - ACH;
        const int row = j * 8 + srow;
        gload16(B + (n0 + row) * (size_t)ldb + k0 + scol, &Bs[buf][j * 512]);
      }
    }
  };

  f32x4 acc[4][NFR] = {};
  stage(0, 0);
  int cur = 0;
  for (int k0 = 0; k0 < Keff; k0 += 64) {
    __syncthreads();  // implicit vmcnt(0): buf[cur] ready; prev readers done
    if (k0 + 64 < Keff) stage(k0 + 64, cur ^ 1);
#pragma unroll
    for (int kk = 0; kk < 2; ++kk) {
      const int ch = (((kk << 2) + hi) ^ rsw) << 3;  // swizzled 16B chunk
      bf16x8 af[4], bfr[NFR];
#pragma unroll
      for (int m = 0; m < 4; ++m)
        af[m] = *(const bf16x8*)&As[cur][(rowbase + m * 16 + lo) * 64 + ch];
#pragma unroll
      for (int n = 0; n < NFR; ++n)
        bfr[n] = *(const bf16x8*)&Bs[cur][(colbase + n * 16 + lo) * 64 + ch];
#pragma unroll
      for (int m = 0; m < 4; ++m)
#pragma unroll
        for (int n = 0; n < NFR; ++n)
          acc[m][n] = __builtin_amdgcn_mfma_f32_16x16x32_bf16(af[m], bfr[n], acc[m][n], 0, 0, 0);
    }
    cur ^= 1;
  }
  float* Cf = (float*)Cv;
  bf16* Cb = (bf16*)Cv;
  const size_t cbase = (size_t)bz * (size_t)bC;
#pragma unroll
  for (int m = 0; m < 4; ++m) {
    const size_t row = m0 + rowbase + m * 16 + hi * 4;
#pragma unroll
    for (int n = 0; n < NFR; ++n) {
      const int col = (int)n0 + colbase + n * 16 + lo;
      if (col < Nreal) {
        const float bv = BIAS ? bias[col] : 0.0f;
#pragma unroll
        for (int j = 0; j < 4; ++j) {
          const float v = acc[m][n][j] + bv;
          const size_t off = cbase + (row + j) * (size_t)ldc + col;
          if (BF16OUT) Cb[off] = __float2bfloat16(v);
          else         Cf[off] = v;
        }
      }
    }
  }
}

// ---------------------------------------------------------------------------
extern "C" void kernel_launch(void* const* d_in, const int* in_sizes, int n_in,
                              void* d_out, int out_size, void* d_ws, size_t ws_size,
                              hipStream_t stream) {
  const float* x       = (const float*)d_in[0];
  const float* wq_a_w  = (const float*)d_in[1];
  const float* wq_a_b  = (const float*)d_in[2];
  const float* q_norm  = (const float*)d_in[3];
  const float* wq_b_w  = (const float*)d_in[4];
  const float* wq_b_b  = (const float*)d_in[5];
  const float* wkv_a_w = (const float*)d_in[6];
  const float* wkv_a_b = (const float*)d_in[7];
  const float* kv_norm = (const float*)d_in[8];
  const float* wkv_b_w = (const float*)d_in[9];
  const float* wo_w    = (const float*)d_in[10];
  const float* wo_bias = (const float*)d_in[11];
  float* out = (float*)d_out;

  char* base = (char*)d_ws;
  // Sbuf: 16 heads x 2048 x 2048 bf16 = 134,217,728 B at offset 0.
  // Transients (all dead before first QK write) alias INSIDE Sbuf:
  bf16*  Sbuf = (bf16*)(base);
  bf16*  xb   = (bf16*)(base + 0);          //  8,388,608
  bf16*  wqa  = (bf16*)(base + 8388608);    //  6,291,456
  bf16*  wqb  = (bf16*)(base + 14680064);   //  9,437,184
  bf16*  wkva = (bf16*)(base + 24117248);   //  2,621,440
  bf16*  wkvb = (bf16*)(base + 26738688);   //  4,194,304
  bf16*  qa   = (bf16*)(base + 30932992);   //  6,291,456
  bf16*  qn   = (bf16*)(base + 37224448);   //  6,291,456
  float* kvf  = (float*)(base + 43515904);  //  5,242,880
  bf16*  kvn  = (bf16*)(base + 48758784);   //  2,097,152  (end 50,855,936)
  // Persistent buffers after Sbuf:
  char* q = base + 134217728;
  bf16* qv   = (bf16*)(q);             q += 12582912;  // 2048x3072
  bf16* Kh   = (bf16*)(q);             q += 12582912;  // 16x2048x192
  bf16* V2T  = (bf16*)(q);             q += 8388608;   // 16x128x2048
  bf16* wob  = (bf16*)(q);             q += 8388608;   // 2048x2048
  bf16* oabs = (bf16*)(q);             q += 8388608;   // 2048x2048

  // all fp32->bf16 converts in one launch
  cvt_all<<<dim3(2048), 256, 0, stream>>>(x, wq_a_w, wq_b_w, wkv_a_w, wkv_b_w, wo_w,
                                          xb, wqa, wqb, wkva, wkvb, wob);

  // q_a = rmsnorm(x @ wq_a^T + b)
  gemm_bt<true, true, 64><<<dim3(12, 32, 1), 256, 0, stream>>>(
      xb, wqa, wq_a_b, qa, 2048, 2048, 1536, 2048, 1536, 0, 0, 0, 0);
  rmsnorm_bf16<<<2048, 256, 0, stream>>>(qa, q_norm, qn, 1536);
  // q = qn @ wq_b^T + b -> qv [2048][3072] (16 heads x 192)
  gemm_bt<true, true, 128><<<dim3(24, 16, 1), 256, 0, stream>>>(
      qn, wqb, wq_b_b, qv, 1536, 1536, 3072, 1536, 3072, 0, 0, 0, 0);
  q_rope<<<2048, 256, 0, stream>>>(qv);
  // kv_full = x @ wkv_a^T + b -> fp32 [2048][640] (576 valid)
  gemm_bt<true, false, 64><<<dim3(5, 32, 1), 256, 0, stream>>>(
      xb, wkva, wkv_a_b, kvf, 2048, 2048, 640, 2048, 576, 0, 0, 0, 0);
  kv_post<<<2048, 256, 0, stream>>>(kvf, kv_norm, kvn, Kh);
  // K_h nope: Kh[h][t][0..128) = kvn[t] . wkvb[h*256+d][:]  (d<128)
  gemm_bt<false, true, 64><<<dim3(1, 32, 16), 256, 0, stream>>>(
      kvn, wkvb, nullptr, Kh, 512, 512, 192, 512, 128,
      0, 256ll * 512, 2048ll * 192, 0);
  // V2T[h][d][t] = wkvb[h*256+128+d][:] . kvn[t][:]
  gemm_bt<false, true, 64><<<dim3(16, 2, 16), 256, 0, stream>>>(
      wkvb + 128ull * 512, kvn, nullptr, V2T, 512, 512, 2048, 512, 2048,
      256ll * 512, 0, 128ll * 2048, 0);

  // ---- attention (decompressed, materialized S), single pass, 16 heads ----
  // S[h][q][t] = q_h[q] . K_h[t]  (K=192), causal block-skip
  gemm_bt<false, true, 128><<<dim3(16, 16, 16), 256, 0, stream>>>(
      qv, Kh, nullptr, Sbuf,
      3072, 192, 2048, 192, 2048,
      192ll, 2048ll * 192, 2048ll * 2048, 1);
  // in-place row softmax with causal mask + 128-tile zero-pad
  softmax_rows<<<dim3(2048, 16), 256, 0, stream>>>(Sbuf);
  // oabs[q][h*128+d] = sum_t P[h][q][t] * V2T[h][d][t], K clamped to m0+64
  gemm_bt<false, true, 64><<<dim3(1, 32, 16), 256, 0, stream>>>(
      Sbuf, V2T, nullptr, oabs,
      2048, 2048, 2048, 2048, 128,
      2048ll * 2048, 128ll * 2048, 128ll, 2);

  // final: out = oabs @ wo^T + b (fp32 out)
  gemm_bt<true, false, 64><<<dim3(16, 32, 1), 256, 0, stream>>>(
      oabs, wob, wo_bias, out, 2048, 2048, 2048, 2048, 2048, 0, 0, 0, 0);
}